// Round 4
// baseline (196.040 us; speedup 1.0000x reference)
//
#include <hip/hip_runtime.h>

// Problem constants: mask_pred (32,16,256,256) f32, pos_gt (32,16,4) int.
constexpr int Wd  = 256;
constexpr int Hd  = 256;
constexpr int BRn = 512;                         // 32*16 images
constexpr long long NTOT = (long long)BRn * Hd * Wd;   // 33,554,432
constexpr int TPB     = 256;
constexpr int NB      = 4096;                    // blocks
constexpr int ITERS   = 8;                       // float4 per thread
constexpr int STRIDE4 = NB * TPB;                // 1,048,576 float4 per sweep (16 MB)
// total f4 = NB*TPB*ITERS = 8,388,608 = 512*256*256/4  ✓ exact cover
constexpr int F4_PER_IMG = Hd * Wd / 4;          // 16384

__global__ __launch_bounds__(TPB)
void crop_ce_partial(const float* __restrict__ mp,
                     const int4* __restrict__ pg4,   // (512) int4 boxes
                     float* __restrict__ partials) {
    const int bid  = blockIdx.x;
    const int tid  = threadIdx.x;
    const int lane = tid & 63;
    const int wid  = tid >> 6;

    // Lockstep sweep: i4(j) = j*STRIDE4 + bid*TPB + tid.
    // img(j) = i4>>14 = 64*j + (bid>>6)        — block-uniform, known now
    // row    = (i4>>6)&255 = (4*bid + wid)&255 — j-invariant, wave-uniform
    // col    = 4*(i4&63)  = 4*lane             — j-invariant
    int4 box[ITERS];
#pragma unroll
    for (int j = 0; j < ITERS; ++j)
        box[j] = pg4[j * (STRIDE4 / F4_PER_IMG) + (bid >> 6)];  // scalar loads

    const int row = (4 * bid + wid) & 255;
    const int col = 4 * lane;

    // Issue all 8 global_load_dwordx4 back-to-back (32 data VGPRs in flight)
    const float4* base4 = (const float4*)mp + (size_t)bid * TPB + tid;
    float4 v[ITERS];
#pragma unroll
    for (int j = 0; j < ITERS; ++j)
        v[j] = base4[(size_t)j * STRIDE4];

    float acc = 0.f;
#pragma unroll
    for (int j = 0; j < ITERS; ++j) {
        const int y0 = box[j].x, x0 = box[j].y, y1 = box[j].z, x1 = box[j].w;
        const bool rin = (row >= y0) & (row <= y1);
        // inside box -> log(p); outside -> log(1-p). One transcendental/elem.
        const float a0 = (rin & (col     >= x0) & (col     <= x1)) ? v[j].x : 1.f - v[j].x;
        const float a1 = (rin & (col + 1 >= x0) & (col + 1 <= x1)) ? v[j].y : 1.f - v[j].y;
        const float a2 = (rin & (col + 2 >= x0) & (col + 2 <= x1)) ? v[j].z : 1.f - v[j].z;
        const float a3 = (rin & (col + 3 >= x0) & (col + 3 <= x1)) ? v[j].w : 1.f - v[j].w;
        acc += __logf(a0) + __logf(a1) + __logf(a2) + __logf(a3);
    }

    // wave-64 shuffle reduction
    for (int off = 32; off; off >>= 1) acc += __shfl_down(acc, off);
    __shared__ float wpart[TPB / 64];
    if (lane == 0) wpart[wid] = acc;
    __syncthreads();

    if (tid == 0) {
        float bs = 0.f;
        for (int k = 0; k < TPB / 64; ++k) bs += wpart[k];
        partials[bid] = bs;   // plain store — no contention, all slots written
    }
}

__global__ __launch_bounds__(TPB)
void crop_ce_final(const float* __restrict__ partials,
                   float* __restrict__ out) {
    // single block: reduce NB floats in double
    double acc = 0.0;
#pragma unroll
    for (int j = 0; j < NB / TPB; ++j)
        acc += (double)partials[j * TPB + (int)threadIdx.x];

    for (int off = 32; off; off >>= 1) acc += __shfl_down(acc, off);
    __shared__ double wpart[TPB / 64];
    const int lane = threadIdx.x & 63;
    const int wid  = threadIdx.x >> 6;
    if (lane == 0) wpart[wid] = acc;
    __syncthreads();

    if (threadIdx.x == 0) {
        double total = 0.0;
        for (int k = 0; k < TPB / 64; ++k) total += wpart[k];
        out[0] = (float)(-total / (double)NTOT);
    }
}

extern "C" void kernel_launch(void* const* d_in, const int* in_sizes, int n_in,
                              void* d_out, int out_size, void* d_ws, size_t ws_size,
                              hipStream_t stream) {
    const float* mp  = (const float*)d_in[0];
    const int4*  pg4 = (const int4*)d_in[1];
    float* out       = (float*)d_out;
    float* partials  = (float*)d_ws;   // NB floats, fully overwritten each launch

    crop_ce_partial<<<NB, TPB, 0, stream>>>(mp, pg4, partials);
    crop_ce_final<<<1, TPB, 0, stream>>>(partials, out);
}

// Round 5
// 189.987 us; speedup vs baseline: 1.0319x; 1.0319x over previous
//
#include <hip/hip_runtime.h>

// Problem constants: mask_pred (32,16,256,256) f32, pos_gt (32,16,4) int.
constexpr int Wd  = 256;
constexpr int Hd  = 256;
constexpr int BRn = 512;                         // 32*16 images
constexpr long long NTOT = (long long)BRn * Hd * Wd;   // 33,554,432
constexpr int F4_PER_IMG   = Hd * Wd / 4;        // 16384 float4 per image
constexpr int CHUNKS       = 8;                  // blocks per image
constexpr int F4_PER_CHUNK = F4_PER_IMG / CHUNKS;// 2048
constexpr int TPB          = 256;
constexpr int ITERS        = F4_PER_CHUNK / TPB; // 8 float4 per thread
constexpr int NBLOCKS      = BRn * CHUNKS;       // 4096 partials

// Best-measured variant (R3, 190.15 us): block-chunked contiguous 32 KB per
// block (spreads blocks across channels; the 16 MB-stride lockstep sweep of
// R4 regressed ~6 us), batched loads, two-kernel contention-free reduction.

__global__ __launch_bounds__(TPB)
void crop_ce_partial(const float* __restrict__ mp,
                     const int* __restrict__ pg,
                     float* __restrict__ partials) {
    const int img   = blockIdx.x;    // which (b,r) image
    const int chunk = blockIdx.y;    // which 1/8 of the image
    const float4* b4 = (const float4*)(mp + (size_t)img * (Hd * Wd));
    const int y0 = pg[img * 4 + 0];
    const int x0 = pg[img * 4 + 1];
    const int y1 = pg[img * 4 + 2];
    const int x1 = pg[img * 4 + 3];

    // Issue all loads back-to-back (8 float4 in flight per wave).
    float4 v[ITERS];
#pragma unroll
    for (int j = 0; j < ITERS; ++j) {
        const int i4 = chunk * F4_PER_CHUNK + j * TPB + (int)threadIdx.x;
        v[j] = b4[i4];
    }

    // inside box -> log(p); outside -> log(1-p). One transcendental/elem.
    float acc = 0.f;
#pragma unroll
    for (int j = 0; j < ITERS; ++j) {
        const int i4 = chunk * F4_PER_CHUNK + j * TPB + (int)threadIdx.x;
        const int idx = i4 * 4;
        const int row = idx >> 8;                 // W = 256
        const int col = idx & 255;
        const bool rin = (row >= y0) & (row <= y1);
        const float a0 = (rin & (col     >= x0) & (col     <= x1)) ? v[j].x : 1.f - v[j].x;
        const float a1 = (rin & (col + 1 >= x0) & (col + 1 <= x1)) ? v[j].y : 1.f - v[j].y;
        const float a2 = (rin & (col + 2 >= x0) & (col + 2 <= x1)) ? v[j].z : 1.f - v[j].z;
        const float a3 = (rin & (col + 3 >= x0) & (col + 3 <= x1)) ? v[j].w : 1.f - v[j].w;
        acc += __logf(a0) + __logf(a1) + __logf(a2) + __logf(a3);
    }

    // wave-64 shuffle reduction
    for (int off = 32; off; off >>= 1) acc += __shfl_down(acc, off);
    __shared__ float wpart[TPB / 64];
    const int lane = threadIdx.x & 63;
    const int wid  = threadIdx.x >> 6;
    if (lane == 0) wpart[wid] = acc;
    __syncthreads();

    if (threadIdx.x == 0) {
        float bs = 0.f;
        for (int k = 0; k < TPB / 64; ++k) bs += wpart[k];
        // plain store — no contention, no pre-zero required (all slots written)
        partials[blockIdx.y * BRn + blockIdx.x] = bs;
    }
}

__global__ __launch_bounds__(TPB)
void crop_ce_final(const float* __restrict__ partials,
                   float* __restrict__ out) {
    // single block: reduce NBLOCKS floats in double
    double acc = 0.0;
#pragma unroll
    for (int j = 0; j < NBLOCKS / TPB; ++j)
        acc += (double)partials[j * TPB + (int)threadIdx.x];

    for (int off = 32; off; off >>= 1) acc += __shfl_down(acc, off);
    __shared__ double wpart[TPB / 64];
    const int lane = threadIdx.x & 63;
    const int wid  = threadIdx.x >> 6;
    if (lane == 0) wpart[wid] = acc;
    __syncthreads();

    if (threadIdx.x == 0) {
        double total = 0.0;
        for (int k = 0; k < TPB / 64; ++k) total += wpart[k];
        out[0] = (float)(-total / (double)NTOT);
    }
}

extern "C" void kernel_launch(void* const* d_in, const int* in_sizes, int n_in,
                              void* d_out, int out_size, void* d_ws, size_t ws_size,
                              hipStream_t stream) {
    const float* mp  = (const float*)d_in[0];
    const int*   pg  = (const int*)d_in[1];
    float* out       = (float*)d_out;
    float* partials  = (float*)d_ws;   // NBLOCKS floats, fully overwritten each launch

    dim3 grid(BRn, CHUNKS);
    crop_ce_partial<<<grid, TPB, 0, stream>>>(mp, pg, partials);
    crop_ce_final<<<1, TPB, 0, stream>>>(partials, out);
}